// Round 5
// baseline (17706.367 us; speedup 1.0000x reference)
//
#include <hip/hip_runtime.h>
#include <math.h>

// Problem constants
static constexpr int H  = 512;
static constexpr int B  = 32;
static constexpr int S  = 128;
static constexpr int G4 = 2048;  // 4*H
static constexpr int BH = B * H;
static constexpr int NBLK = 32;  // persistent grid size (1 block per 16 units)

// ws layout (floats)
static constexpr size_t OFF_E   = 0;                         // E [t][c][b]; reused as D [b][t][c]
static constexpr size_t SZ_E    = (size_t)S * G4 * B;        // 8,388,608
static constexpr size_t OFF_EO  = OFF_E + SZ_E;              // enc_out [b][t][h]
static constexpr size_t SZ_EO   = (size_t)B * S * H;
static constexpr size_t OFF_PT  = OFF_EO + SZ_EO;            // P_t [b][h][s]
static constexpr size_t SZ_PT   = (size_t)B * H * S;
static constexpr size_t OFF_W2T = OFF_PT + SZ_PT;            // W2T [512][512]
static constexpr size_t OFF_H   = OFF_W2T + (size_t)H * H;   // h ping-pong [2][B][H]
static constexpr size_t OFF_CB  = OFF_H + 2 * (size_t)BH;    // c_buf [b][h]
static constexpr size_t OFF_PDP = OFF_CB + (size_t)BH;       // pdp [2][b][part=32][n=512]
static constexpr size_t SZ_PDP  = 2 * (size_t)B * 32 * 512;
static constexpr size_t OFF_M1  = OFF_PDP + SZ_PDP;          // M1 [c][2]
static constexpr size_t OFF_BE  = OFF_M1 + (size_t)G4 * 2;   // bias_e [c]
static constexpr size_t OFF_DB  = OFF_BE + G4;               // dbias [c]
static constexpr size_t OFF_END = OFF_DB + G4;               // floats end
// u32 region at OFF_END: slots_e[32*32], slots_d[32*32], tops[32*32]
static constexpr int CTRL_U32 = 3 * 32 * 32;

__device__ __forceinline__ float sigm(float x){
  float e = __expf(-x);
  return 1.0f / (1.0f + e);
}
__device__ __forceinline__ float tanh_(float x){
  float e = __expf(2.0f * x);
  return 1.0f - 2.0f / (1.0f + e);
}

// agent-scope (coherence-point) accessors — no fences needed with the
// __syncthreads-before-signal discipline (drains vmcnt; validated r1-r4)
__device__ __forceinline__ float2 cload2(const float* p){
  union { unsigned long long u; float2 f; } c;
  c.u = __hip_atomic_load((const unsigned long long*)p, __ATOMIC_RELAXED,
                          __HIP_MEMORY_SCOPE_AGENT);
  return c.f;
}
__device__ __forceinline__ void cstore(float* p, float v){
  __hip_atomic_store(p, v, __ATOMIC_RELAXED, __HIP_MEMORY_SCOPE_AGENT);
}
__device__ __forceinline__ void cstore2(float* p, float a, float b){
  union { unsigned long long u; float2 f; } c;
  c.f = make_float2(a, b);
  __hip_atomic_store((unsigned long long*)p, c.u, __ATOMIC_RELAXED,
                     __HIP_MEMORY_SCOPE_AGENT);
}

// -------- flat grid barrier for NBLK=32 co-resident blocks --------
// Arrival: 1 store to own 128B line. Detection: lanes 0..31 poll all slots
// in parallel (no master, no release hop). __syncthreads drains vmcnt so
// prior agent-scope data stores are at the coherence point before arrival.
__device__ __forceinline__ void fbar(unsigned* slots, unsigned ep){
  __syncthreads();
  if (threadIdx.x == 0)
    __hip_atomic_store(slots + blockIdx.x * 32, ep, __ATOMIC_RELAXED,
                       __HIP_MEMORY_SCOPE_AGENT);
  if (threadIdx.x < NBLK){
    while (__hip_atomic_load(slots + threadIdx.x * 32, __ATOMIC_RELAXED,
                             __HIP_MEMORY_SCOPE_AGENT) < ep){}
  }
  __syncthreads();
}

// -------- prep: M1 = Wih@Wp, bias_e = Wih@bp + bih + bhh, dbias --------
__global__ __launch_bounds__(256) void prep_misc(
    const float* __restrict__ eWih, const float* __restrict__ Wp,
    const float* __restrict__ bp,  const float* __restrict__ ebih,
    const float* __restrict__ ebhh, const float* __restrict__ dbih,
    const float* __restrict__ dbhh,
    float* __restrict__ M1, float* __restrict__ bias_e, float* __restrict__ dbias)
{
  int c = blockIdx.x * 256 + threadIdx.x;   // 0..2047
  const float* wr = eWih + (size_t)c * H;
  float m0 = 0.f, m1 = 0.f, mb = 0.f;
  for (int k = 0; k < H; k += 4){
    float4 w  = *(const float4*)(wr + k);
    float4 p0 = *(const float4*)(Wp + (size_t)k * 2);
    float4 p1 = *(const float4*)(Wp + (size_t)(k + 2) * 2);
    float4 bb = *(const float4*)(bp + k);
    m0 += w.x*p0.x + w.y*p0.z + w.z*p1.x + w.w*p1.z;
    m1 += w.x*p0.y + w.y*p0.w + w.z*p1.y + w.w*p1.w;
    mb += w.x*bb.x + w.y*bb.y + w.z*bb.z + w.w*bb.w;
  }
  M1[(size_t)c*2]   = m0;
  M1[(size_t)c*2+1] = m1;
  bias_e[c] = ebih[c] + ebhh[c] + mb;
  dbias[c]  = dbih[c] + dbhh[c];
}

// -------- E fill: E[t][c][b] = M1[c]·in[b,t] + bias_e[c] --------
__global__ __launch_bounds__(256) void efill(
    const float* __restrict__ inp, const float* __restrict__ M1,
    const float* __restrict__ be, float* __restrict__ E)
{
  size_t i = (size_t)blockIdx.x * 256 + threadIdx.x;
  int b = (int)(i & 31);
  int c = (int)((i >> 5) & 2047);
  int t = (int)(i >> 16);
  float x0 = inp[((size_t)b * S + t) * 2 + 0];
  float x1 = inp[((size_t)b * S + t) * 2 + 1];
  E[i] = M1[(size_t)c*2] * x0 + M1[(size_t)c*2+1] * x1 + be[c];
}

// -------- transpose: out[K][R] = in[R][K] --------
__global__ __launch_bounds__(256) void transpose_k(
    const float* __restrict__ in, float* __restrict__ out, int R, int K)
{
  __shared__ float tile[32][33];
  int r0 = blockIdx.y * 32, k0 = blockIdx.x * 32;
  int tx = threadIdx.x & 31, ty = threadIdx.x >> 5;
  #pragma unroll
  for (int j = 0; j < 4; ++j)
    tile[ty + 8*j][tx] = in[(size_t)(r0 + ty + 8*j) * K + k0 + tx];
  __syncthreads();
  #pragma unroll
  for (int j = 0; j < 4; ++j)
    out[(size_t)(k0 + ty + 8*j) * R + r0 + tx] = tile[tx][ty + 8*j];
}

// -------- generic fp32 GEMM: C = A(MxK) @ B(NxK)^T (+bias) --------
template<int LAYOUT>
__global__ __launch_bounds__(256) void gemm_nt(
    const float* __restrict__ A, const float* __restrict__ Bm,
    const float* __restrict__ bias, float* __restrict__ C,
    int M, int N, int K)
{
  __shared__ float As[16][68];
  __shared__ float Bs[16][68];
  int tid = threadIdx.x;
  int bm = blockIdx.y * 64, bn = blockIdx.x * 64;
  int tm = (tid & 15) * 4, tn = (tid >> 4) * 4;
  float acc[4][4] = {};
  int r  = tid >> 2;
  int kq = (tid & 3) * 4;
  for (int k0 = 0; k0 < K; k0 += 16){
    float4 a = *(const float4*)(A  + (size_t)(bm + r) * K + k0 + kq);
    float4 b = *(const float4*)(Bm + (size_t)(bn + r) * K + k0 + kq);
    __syncthreads();
    As[kq+0][r] = a.x; As[kq+1][r] = a.y; As[kq+2][r] = a.z; As[kq+3][r] = a.w;
    Bs[kq+0][r] = b.x; Bs[kq+1][r] = b.y; Bs[kq+2][r] = b.z; Bs[kq+3][r] = b.w;
    __syncthreads();
    #pragma unroll
    for (int kk = 0; kk < 16; ++kk){
      float4 av = *(const float4*)(&As[kk][tm]);
      float4 bv = *(const float4*)(&Bs[kk][tn]);
      acc[0][0] += av.x*bv.x; acc[0][1] += av.x*bv.y; acc[0][2] += av.x*bv.z; acc[0][3] += av.x*bv.w;
      acc[1][0] += av.y*bv.x; acc[1][1] += av.y*bv.y; acc[1][2] += av.y*bv.z; acc[1][3] += av.y*bv.w;
      acc[2][0] += av.z*bv.x; acc[2][1] += av.z*bv.y; acc[2][2] += av.z*bv.z; acc[2][3] += av.z*bv.w;
      acc[3][0] += av.w*bv.x; acc[3][1] += av.w*bv.y; acc[3][2] += av.w*bv.z; acc[3][3] += av.w*bv.w;
    }
  }
  #pragma unroll
  for (int i = 0; i < 4; ++i){
    int m = bm + tm + i;
    #pragma unroll
    for (int j = 0; j < 4; ++j){
      int n = bn + tn + j;
      float vv = acc[i][j] + (bias ? bias[n] : 0.f);
      if (LAYOUT == 0) C[(size_t)m * N + n] = vv;
      else             C[((size_t)(m >> 7) * 512 + n) * 128 + (m & 127)] = vv;
    }
  }
}

// stage h (agent-coherent, [B][H]) into XOR-swizzled LDS
__device__ __forceinline__ void stage_h(const float* hsrc, float* hsh, int tid){
  #pragma unroll
  for (int i = tid; i < BH / 4; i += 256){
    int bb = i >> 7, k4 = i & 127;
    const float* src = hsrc + (size_t)bb * H + (k4 << 2);
    float2 lo = cload2(src), hi = cload2(src + 2);
    float4 vv; vv.x = lo.x; vv.y = lo.y; vv.z = hi.x; vv.w = hi.y;
    *(float4*)&hsh[bb * H + ((k4 ^ (bb & 7)) << 2)] = vv;
  }
}

// gates GEMV: block bk owns units [bk*16, bk*16+16) => 64 Whh rows.
// thread (b = tid&31, z = tid>>5): 8 rows (row_local = z*8+rr),
// g = row_local>>4, ul = row_local&15, weight row = g*512 + bk*16 + ul.
// Weight rows uniform across the 32 b-lanes -> L1 broadcast.
__device__ __forceinline__ void gemv64(
    const float* __restrict__ W,   // [2048][512] row-major
    const float* hsh, int bk, int b, int z, float acc[8])
{
  const int bx = b & 7;
  const float* hb = hsh + b * H;
  const float* wr[8];
  #pragma unroll
  for (int rr = 0; rr < 8; ++rr){
    int rl = z * 8 + rr;
    wr[rr] = W + (size_t)((rl >> 4) * 512 + bk * 16 + (rl & 15)) * H;
  }
  #pragma unroll
  for (int rr = 0; rr < 8; ++rr) acc[rr] = 0.f;
  #pragma unroll 2
  for (int k4 = 0; k4 < 128; ++k4){
    float4 hv = *(const float4*)(hb + ((k4 ^ bx) << 2));
    #pragma unroll
    for (int rr = 0; rr < 8; ++rr){
      float4 w = *(const float4*)(wr[rr] + (k4 << 2));
      acc[rr] = fmaf(w.w, hv.w, fmaf(w.z, hv.z, fmaf(w.y, hv.y, fmaf(w.x, hv.x, acc[rr]))));
    }
  }
}

// -------- persistent encoder: grid=32, 1 flat barrier/step --------
__global__ __launch_bounds__(256) void encoder_kernel(
    const float* __restrict__ Whh,    // enc_Whh [2048][512]
    const float* __restrict__ E,      // [t][c][b]
    float* __restrict__ h_pp,         // [2][B][H] (zeroed; final h -> h_pp[1])
    float* __restrict__ c_buf,        // [b][h]
    float* __restrict__ enc_out,      // [b][t][h]
    unsigned* __restrict__ slots)
{
  __shared__ float hsh[BH];           // 64KB
  __shared__ float gsh[4][16][B];     // 8KB
  const int tid = threadIdx.x, bk = blockIdx.x;
  const int b = tid & 31, z = tid >> 5;
  const int u0 = bk * 16;
  float c0 = 0.f, c1 = 0.f;
  for (int t = 0; t < S; ++t){
    const float* hsrc = h_pp + (size_t)((t & 1) ^ 1) * BH;
    float*       hdst = h_pp + (size_t)(t & 1) * BH;
    stage_h(hsrc, hsh, tid);
    __syncthreads();
    float acc[8];
    gemv64(Whh, hsh, bk, b, z, acc);
    #pragma unroll
    for (int rr = 0; rr < 8; ++rr){
      int rl = z * 8 + rr;
      int row = (rl >> 4) * 512 + u0 + (rl & 15);
      gsh[rl >> 4][rl & 15][b] = acc[rr] + E[((size_t)t * G4 + row) * B + b];
    }
    __syncthreads();
    #pragma unroll
    for (int q = 0; q < 2; ++q){
      int u = z * 2 + q;
      float gi = gsh[0][u][b], gf = gsh[1][u][b],
            gg = gsh[2][u][b], go = gsh[3][u][b];
      float& cc = q ? c1 : c0;
      cc = sigm(gf) * cc + sigm(gi) * tanh_(gg);
      float hn = sigm(go) * tanh_(cc);
      cstore(hdst + (size_t)b * H + u0 + u, hn);
      enc_out[((size_t)b * S + t) * H + u0 + u] = hn;
    }
    fbar(slots, (unsigned)(t + 1));
  }
  c_buf[(size_t)b * H + u0 + z * 2]     = c0;
  c_buf[(size_t)b * H + u0 + z * 2 + 1] = c1;
}

// -------- persistent decoder: grid=32, ONE barrier/step --------
// Step t: [stage h][gates GEMV (3.4us)][poll top tags (hidden)][+xterm]
// [pointwise -> h][partial-dp rank-16 update][fbar][C: dp-sum+attn+argmax,
// publish (tag<<8|idx)]. Safety: any block past fbar(t+1) implies all blocks
// finished A_t (so h/pdp parity buffers are safe to overwrite); top-tag poll
// carries the C->A data edge with its latency hidden under the GEMV.
__global__ __launch_bounds__(256) void decoder_kernel(
    const float* __restrict__ Whh,    // dec_Whh [2048][512]
    const float* __restrict__ D,      // [b][t][c]
    const float* __restrict__ dbias,  // [2048]
    const float* __restrict__ W2T,    // [512][512] = W2^T
    const float* __restrict__ Pt,     // [b][h][s]
    const float* __restrict__ vvec,   // [512]
    const float* __restrict__ c_buf,  // [b][h]
    float* __restrict__ h_pp,         // [2][B][H]; h_pp[1] = enc final h
    float* __restrict__ pdp,          // [2][B][32][512]
    unsigned* __restrict__ tops,      // [32] lines
    float* __restrict__ out,          // [b][t][s]
    unsigned* __restrict__ slots)
{
  __shared__ float hsh[BH];
  __shared__ float gsh[4][16][B];
  __shared__ float hloc[B][16];
  __shared__ int   topsh[B];
  __shared__ float dpsh[H];
  __shared__ float vsh[H];
  __shared__ float scsh[2][S];
  __shared__ float wm[2]; __shared__ int wi[2]; __shared__ float wsum[2];
  const int tid = threadIdx.x, bk = blockIdx.x;
  const int b = tid & 31, z = tid >> 5;
  const int u0 = bk * 16;
  vsh[tid] = vvec[tid]; vsh[tid + 256] = vvec[tid + 256];
  float c0 = c_buf[(size_t)b * H + u0 + z * 2];
  float c1 = c_buf[(size_t)b * H + u0 + z * 2 + 1];
  for (int t = 0; t < S; ++t){
    const float* hsrc = h_pp + (size_t)((t & 1) ^ 1) * BH;  // t=0 -> h_pp[1]
    float*       hdst = h_pp + (size_t)(t & 1) * BH;
    float*       pdp_w = pdp + (size_t)(t & 1) * B * 32 * 512;
    // ---- phase A ----
    stage_h(hsrc, hsh, tid);
    __syncthreads();
    float acc[8];
    gemv64(Whh, hsh, bk, b, z, acc);
    if (t > 0 && tid < 32){
      unsigned vt;
      do {
        vt = __hip_atomic_load(tops + tid * 32, __ATOMIC_RELAXED,
                               __HIP_MEMORY_SCOPE_AGENT);
      } while ((vt >> 8) != (unsigned)t);
      topsh[tid] = (int)(vt & 255u);
    }
    __syncthreads();
    #pragma unroll
    for (int rr = 0; rr < 8; ++rr){
      int rl = z * 8 + rr;
      int row = (rl >> 4) * 512 + u0 + (rl & 15);
      float xt = (t == 0) ? dbias[row]
                          : D[((size_t)b * S + topsh[b]) * G4 + row];
      gsh[rl >> 4][rl & 15][b] = acc[rr] + xt;
    }
    __syncthreads();
    #pragma unroll
    for (int q = 0; q < 2; ++q){
      int u = z * 2 + q;
      float gi = gsh[0][u][b], gf = gsh[1][u][b],
            gg = gsh[2][u][b], go = gsh[3][u][b];
      float& cc = q ? c1 : c0;
      cc = sigm(gf) * cc + sigm(gi) * tanh_(gg);
      float hn = sigm(go) * tanh_(cc);
      hloc[b][u] = hn;
      cstore(hdst + (size_t)b * H + u0 + u, hn);
    }
    __syncthreads();
    // partial dp: thread (bb = tid>>3, nc = tid&7) -> n in [nc*64, nc*64+64)
    {
      int bb = tid >> 3, nc = tid & 7;
      float hv[16];
      #pragma unroll
      for (int j = 0; j < 16; ++j) hv[j] = hloc[bb][j];
      float* dst = pdp_w + ((size_t)bb * 32 + bk) * 512 + nc * 64;
      for (int nn = 0; nn < 64; nn += 4){
        float4 s2 = {0.f, 0.f, 0.f, 0.f};
        #pragma unroll
        for (int j = 0; j < 16; ++j){
          float4 w = *(const float4*)(W2T + (size_t)(u0 + j) * H + nc * 64 + nn);
          s2.x = fmaf(w.x, hv[j], s2.x); s2.y = fmaf(w.y, hv[j], s2.y);
          s2.z = fmaf(w.z, hv[j], s2.z); s2.w = fmaf(w.w, hv[j], s2.w);
        }
        cstore2(dst + nn,     s2.x, s2.y);
        cstore2(dst + nn + 2, s2.z, s2.w);
      }
    }
    fbar(slots, (unsigned)(t + 1));
    // ---- phase C: this block handles batch bk ----
    {
      int n0 = tid * 2;
      float s0 = 0.f, s1 = 0.f;
      const float* pr = pdp_w + (size_t)bk * 32 * 512 + n0;
      #pragma unroll 4
      for (int p = 0; p < 32; ++p){
        float2 q2 = cload2(pr + (size_t)p * 512);
        s0 += q2.x; s1 += q2.y;
      }
      dpsh[n0] = s0; dpsh[n0 + 1] = s1;
    }
    __syncthreads();
    {
      int s = tid & 127, half = tid >> 7;
      const float* Pp = Pt + ((size_t)bk * H + half * 256) * S + s;
      const float* dq = dpsh + half * 256;
      const float* vq = vsh + half * 256;
      float cs = 0.f;
      #pragma unroll 4
      for (int hh = 0; hh < 256; ++hh){
        float x = Pp[(size_t)hh * S] + dq[hh];
        cs = fmaf(vq[hh], tanh_(x), cs);
      }
      scsh[half][s] = cs;
    }
    __syncthreads();
    float sc = 0.f;
    if (tid < 128){
      sc = scsh[0][tid] + scsh[1][tid];
      float mv = sc; int mi = tid;
      #pragma unroll
      for (int off = 32; off > 0; off >>= 1){
        float ov = __shfl_xor(mv, off, 64);
        int   oi = __shfl_xor(mi, off, 64);
        if (ov > mv || (ov == mv && oi < mi)){ mv = ov; mi = oi; }
      }
      if ((tid & 63) == 0){ wm[tid >> 6] = mv; wi[tid >> 6] = mi; }
    }
    __syncthreads();
    float m; int am;
    {
      float m0 = wm[0], m1 = wm[1];
      if (m1 > m0 || (m1 == m0 && wi[1] < wi[0])){ m = m1; am = wi[1]; }
      else { m = m0; am = wi[0]; }
    }
    if (tid < 128){
      float se = __expf(sc - m);
      float ss = se;
      #pragma unroll
      for (int off = 32; off > 0; off >>= 1) ss += __shfl_xor(ss, off, 64);
      if ((tid & 63) == 0) wsum[tid >> 6] = ss;
    }
    __syncthreads();
    float lse = __logf(wsum[0] + wsum[1]);
    if (tid < 128) out[((size_t)bk * S + t) * S + tid] = sc - m - lse;
    if (tid == 0)
      __hip_atomic_store(tops + bk * 32,
                         ((unsigned)(t + 1) << 8) | (unsigned)am,
                         __ATOMIC_RELAXED, __HIP_MEMORY_SCOPE_AGENT);
    __syncthreads();
  }
}

extern "C" void kernel_launch(void* const* d_in, const int* in_sizes, int n_in,
                              void* d_out, int out_size, void* d_ws, size_t ws_size,
                              hipStream_t stream) {
  const float* inputs  = (const float*)d_in[0];
  const float* Wp      = (const float*)d_in[1];
  const float* bp      = (const float*)d_in[2];
  const float* eWih    = (const float*)d_in[3];
  const float* eWhh    = (const float*)d_in[4];
  const float* ebih    = (const float*)d_in[5];
  const float* ebhh    = (const float*)d_in[6];
  const float* dWih    = (const float*)d_in[7];
  const float* dWhh    = (const float*)d_in[8];
  const float* dbih    = (const float*)d_in[9];
  const float* dbhh    = (const float*)d_in[10];
  const float* W1      = (const float*)d_in[11];
  const float* W2      = (const float*)d_in[12];
  const float* v       = (const float*)d_in[13];
  float* out = (float*)d_out;

  float* ws = (float*)d_ws;
  float* E       = ws + OFF_E;    // reused as D after encoder
  float* enc_out = ws + OFF_EO;
  float* Pt      = ws + OFF_PT;
  float* W2T     = ws + OFF_W2T;
  float* h_pp    = ws + OFF_H;
  float* c_buf   = ws + OFF_CB;
  float* pdp     = ws + OFF_PDP;
  float* M1      = ws + OFF_M1;
  float* bias_e  = ws + OFF_BE;
  float* dbias   = ws + OFF_DB;
  unsigned* slots_e = (unsigned*)(ws + OFF_END);
  unsigned* slots_d = slots_e + 32 * 32;
  unsigned* tops    = slots_d + 32 * 32;

  // deterministic per launch: zero h ping-pong + all control words
  hipMemsetAsync(h_pp, 0, 2 * (size_t)BH * sizeof(float), stream);
  hipMemsetAsync(slots_e, 0, CTRL_U32 * sizeof(unsigned), stream);

  prep_misc<<<G4 / 256, 256, 0, stream>>>(eWih, Wp, bp, ebih, ebhh, dbih, dbhh,
                                          M1, bias_e, dbias);
  efill<<<(int)(SZ_E / 256), 256, 0, stream>>>(inputs, M1, bias_e, E);
  { dim3 g(H / 32, H / 32); transpose_k<<<g, 256, 0, stream>>>(W2, W2T, H, H); }

  encoder_kernel<<<NBLK, 256, 0, stream>>>(eWhh, E, h_pp, c_buf, enc_out, slots_e);

  // D = enc_out @ dWih^T + dbias (into E's buffer; encoder is done with E)
  float* D = E;
  { dim3 grid(G4 / 64, (B * S) / 64);
    gemm_nt<0><<<grid, 256, 0, stream>>>(enc_out, dWih, dbias, D, B * S, G4, H); }
  { dim3 grid(H / 64, (B * S) / 64);
    gemm_nt<1><<<grid, 256, 0, stream>>>(enc_out, W1, nullptr, Pt, B * S, H, H); }

  decoder_kernel<<<NBLK, 256, 0, stream>>>(dWhh, D, dbias, W2T, Pt, v,
                                           c_buf, h_pp, pdp, tops, out, slots_d);
  (void)in_sizes; (void)n_in; (void)out_size; (void)ws_size;
}

// Round 6
// 6311.036 us; speedup vs baseline: 2.8056x; 2.8056x over previous
//
#include <hip/hip_runtime.h>
#include <math.h>

// Problem constants
static constexpr int H  = 512;
static constexpr int B  = 32;
static constexpr int S  = 128;
static constexpr int G4 = 2048;  // 4*H
static constexpr int BH = B * H; // 16384

// ws layout (floats)
static constexpr size_t OFF_E   = 0;                        // E [t][c][b]; reused as D [b][t][c]
static constexpr size_t SZ_E    = (size_t)S * G4 * B;       // 8,388,608
static constexpr size_t OFF_EO  = OFF_E + SZ_E;             // enc_out [b][t][h]
static constexpr size_t SZ_EO   = (size_t)B * S * H;
static constexpr size_t OFF_PT  = OFF_EO + SZ_EO;           // P_t [b][h][s]
static constexpr size_t SZ_PT   = (size_t)B * H * S;
static constexpr size_t OFF_H   = OFF_PT + SZ_PT;           // h ping-pong [2][B][H]
static constexpr size_t OFF_CB  = OFF_H + 2 * (size_t)BH;   // c_buf [b][h]
static constexpr size_t OFF_DP  = OFF_CB + (size_t)BH;      // dp [2][B][H]
static constexpr size_t OFF_M1  = OFF_DP + 2 * (size_t)BH;  // M1 [c][2]
static constexpr size_t OFF_BE  = OFF_M1 + (size_t)G4 * 2;  // bias_e [c]
static constexpr size_t OFF_DB  = OFF_BE + G4;              // dbias [c]
static constexpr size_t OFF_END = OFF_DB + G4;              // floats end
// u32 ctrl at OFF_END: enc_htags[256*32], dec_htags[256*32], btags[128*32], tops[32*32]
static constexpr int CTRL_U32 = (256 + 256 + 128 + 32) * 32;  // 21504

__device__ __forceinline__ float sigm(float x){
  float e = __expf(-x);
  return 1.0f / (1.0f + e);
}
__device__ __forceinline__ float tanh_(float x){
  float e = __expf(2.0f * x);
  return 1.0f - 2.0f / (1.0f + e);
}

// agent-scope (coherence-point) accessors; discipline: __syncthreads (vmcnt
// drain) between data stores and the tag store (validated r2-r5)
__device__ __forceinline__ float2 cload2(const float* p){
  union { unsigned long long u; float2 f; } c;
  c.u = __hip_atomic_load((const unsigned long long*)p, __ATOMIC_RELAXED,
                          __HIP_MEMORY_SCOPE_AGENT);
  return c.f;
}
__device__ __forceinline__ void cstore(float* p, float v){
  __hip_atomic_store(p, v, __ATOMIC_RELAXED, __HIP_MEMORY_SCOPE_AGENT);
}
__device__ __forceinline__ void cstore2(float* p, float a, float b){
  union { unsigned long long u; float2 f; } c;
  c.f = make_float2(a, b);
  __hip_atomic_store((unsigned long long*)p, c.u, __ATOMIC_RELAXED,
                     __HIP_MEMORY_SCOPE_AGENT);
}
__device__ __forceinline__ unsigned cloadu(const unsigned* p){
  return __hip_atomic_load(p, __ATOMIC_RELAXED, __HIP_MEMORY_SCOPE_AGENT);
}
__device__ __forceinline__ void cstoreu(unsigned* p, unsigned v){
  __hip_atomic_store(p, v, __ATOMIC_RELAXED, __HIP_MEMORY_SCOPE_AGENT);
}

// poll NQ tags (lines tid, tid+64, ...) until all >= target; caller: tid<64
template<int NQ>
__device__ __forceinline__ void pollN(const unsigned* base, int tid, unsigned target){
  unsigned done = 0;
  const unsigned all = (1u << NQ) - 1u;
  while (done != all){
    #pragma unroll
    for (int q = 0; q < NQ; ++q){
      if (!(done & (1u << q))){
        if (cloadu(base + (size_t)(tid + 64 * q) * 32) >= target) done |= 1u << q;
      }
    }
  }
}

// -------- prep: M1 = Wih@Wp, bias_e = Wih@bp + bih + bhh, dbias --------
__global__ __launch_bounds__(256) void prep_misc(
    const float* __restrict__ eWih, const float* __restrict__ Wp,
    const float* __restrict__ bp,  const float* __restrict__ ebih,
    const float* __restrict__ ebhh, const float* __restrict__ dbih,
    const float* __restrict__ dbhh,
    float* __restrict__ M1, float* __restrict__ bias_e, float* __restrict__ dbias)
{
  int c = blockIdx.x * 256 + threadIdx.x;   // 0..2047
  const float* wr = eWih + (size_t)c * H;
  float m0 = 0.f, m1 = 0.f, mb = 0.f;
  for (int k = 0; k < H; k += 4){
    float4 w  = *(const float4*)(wr + k);
    float4 p0 = *(const float4*)(Wp + (size_t)k * 2);
    float4 p1 = *(const float4*)(Wp + (size_t)(k + 2) * 2);
    float4 bb = *(const float4*)(bp + k);
    m0 += w.x*p0.x + w.y*p0.z + w.z*p1.x + w.w*p1.z;
    m1 += w.x*p0.y + w.y*p0.w + w.z*p1.y + w.w*p1.w;
    mb += w.x*bb.x + w.y*bb.y + w.z*bb.z + w.w*bb.w;
  }
  M1[(size_t)c*2]   = m0;
  M1[(size_t)c*2+1] = m1;
  bias_e[c] = ebih[c] + ebhh[c] + mb;
  dbias[c]  = dbih[c] + dbhh[c];
}

// -------- E fill: E[t][c][b] = M1[c]·in[b,t] + bias_e[c] --------
__global__ __launch_bounds__(256) void efill(
    const float* __restrict__ inp, const float* __restrict__ M1,
    const float* __restrict__ be, float* __restrict__ E)
{
  size_t i = (size_t)blockIdx.x * 256 + threadIdx.x;
  int b = (int)(i & 31);
  int c = (int)((i >> 5) & 2047);
  int t = (int)(i >> 16);
  float x0 = inp[((size_t)b * S + t) * 2 + 0];
  float x1 = inp[((size_t)b * S + t) * 2 + 1];
  E[i] = M1[(size_t)c*2] * x0 + M1[(size_t)c*2+1] * x1 + be[c];
}

// -------- generic fp32 GEMM: C = A(MxK) @ B(NxK)^T (+bias) --------
// LAYOUT 0: C[m*N+n]   LAYOUT 1: Pt[b][n][t] with m = b*128+t
template<int LAYOUT>
__global__ __launch_bounds__(256) void gemm_nt(
    const float* __restrict__ A, const float* __restrict__ Bm,
    const float* __restrict__ bias, float* __restrict__ C,
    int M, int N, int K)
{
  __shared__ float As[16][68];
  __shared__ float Bs[16][68];
  int tid = threadIdx.x;
  int bm = blockIdx.y * 64, bn = blockIdx.x * 64;
  int tm = (tid & 15) * 4, tn = (tid >> 4) * 4;
  float acc[4][4] = {};
  int r  = tid >> 2;
  int kq = (tid & 3) * 4;
  for (int k0 = 0; k0 < K; k0 += 16){
    float4 a = *(const float4*)(A  + (size_t)(bm + r) * K + k0 + kq);
    float4 b = *(const float4*)(Bm + (size_t)(bn + r) * K + k0 + kq);
    __syncthreads();
    As[kq+0][r] = a.x; As[kq+1][r] = a.y; As[kq+2][r] = a.z; As[kq+3][r] = a.w;
    Bs[kq+0][r] = b.x; Bs[kq+1][r] = b.y; Bs[kq+2][r] = b.z; Bs[kq+3][r] = b.w;
    __syncthreads();
    #pragma unroll
    for (int kk = 0; kk < 16; ++kk){
      float4 av = *(const float4*)(&As[kk][tm]);
      float4 bv = *(const float4*)(&Bs[kk][tn]);
      acc[0][0] += av.x*bv.x; acc[0][1] += av.x*bv.y; acc[0][2] += av.x*bv.z; acc[0][3] += av.x*bv.w;
      acc[1][0] += av.y*bv.x; acc[1][1] += av.y*bv.y; acc[1][2] += av.y*bv.z; acc[1][3] += av.y*bv.w;
      acc[2][0] += av.z*bv.x; acc[2][1] += av.z*bv.y; acc[2][2] += av.z*bv.z; acc[2][3] += av.z*bv.w;
      acc[3][0] += av.w*bv.x; acc[3][1] += av.w*bv.y; acc[3][2] += av.w*bv.z; acc[3][3] += av.w*bv.w;
    }
  }
  #pragma unroll
  for (int i = 0; i < 4; ++i){
    int m = bm + tm + i;
    #pragma unroll
    for (int j = 0; j < 4; ++j){
      int n = bn + tn + j;
      float vv = acc[i][j] + (bias ? bias[n] : 0.f);
      if (LAYOUT == 0) C[(size_t)m * N + n] = vv;
      else             C[((size_t)(m >> 7) * 512 + n) * 128 + (m & 127)] = vv;
    }
  }
}

// stage h (agent-coherent, [B][H]) into XOR-swizzled LDS
__device__ __forceinline__ void stage_h(const float* hsrc, float* hsh, int tid){
  #pragma unroll
  for (int i = tid; i < BH / 4; i += 256){
    int bb = i >> 7, k4 = i & 127;
    const float* src = hsrc + (size_t)bb * H + (k4 << 2);
    float2 lo = cload2(src), hi = cload2(src + 2);
    float4 vv; vv.x = lo.x; vv.y = lo.y; vv.z = hi.x; vv.w = hi.y;
    *(float4*)&hsh[bb * H + ((k4 ^ (bb & 7)) << 2)] = vv;
  }
}

// one-row GEMV vs swizzled LDS h-row (r3's proven inner loop)
__device__ __forceinline__ float gemv_row(const float* __restrict__ wrow,
                                          const float* __restrict__ hb, int bx){
  float a0=0.f,a1=0.f,a2=0.f,a3=0.f;
  #pragma unroll 2
  for (int k4 = 0; k4 < 128; k4 += 4){
    float4 w0 = *(const float4*)(wrow + ((k4+0) << 2));
    float4 q0 = *(const float4*)(hb + (((k4+0) ^ bx) << 2));
    a0 = fmaf(w0.w,q0.w, fmaf(w0.z,q0.z, fmaf(w0.y,q0.y, fmaf(w0.x,q0.x, a0))));
    float4 w1 = *(const float4*)(wrow + ((k4+1) << 2));
    float4 q1 = *(const float4*)(hb + (((k4+1) ^ bx) << 2));
    a1 = fmaf(w1.w,q1.w, fmaf(w1.z,q1.z, fmaf(w1.y,q1.y, fmaf(w1.x,q1.x, a1))));
    float4 w2 = *(const float4*)(wrow + ((k4+2) << 2));
    float4 q2 = *(const float4*)(hb + (((k4+2) ^ bx) << 2));
    a2 = fmaf(w2.w,q2.w, fmaf(w2.z,q2.z, fmaf(w2.y,q2.y, fmaf(w2.x,q2.x, a2))));
    float4 w3 = *(const float4*)(wrow + ((k4+3) << 2));
    float4 q3 = *(const float4*)(hb + (((k4+3) ^ bx) << 2));
    a3 = fmaf(w3.w,q3.w, fmaf(w3.z,q3.z, fmaf(w3.y,q3.y, fmaf(w3.x,q3.x, a3))));
  }
  return (a0 + a1) + (a2 + a3);
}

// -------- persistent encoder: grid=256, tag dataflow (no barriers) --------
__global__ __launch_bounds__(256) void encoder_kernel(
    const float* __restrict__ Whh,    // enc_Whh [2048][512]
    const float* __restrict__ E,      // [t][c][b]
    float* __restrict__ h_pp,         // [2][B][H]; zeroed; final h -> h_pp[1]
    float* __restrict__ c_buf,        // [b][h]
    float* __restrict__ enc_out,      // [b][t][h]
    unsigned* __restrict__ htags)     // [256] lines
{
  __shared__ float hsh[BH];
  __shared__ float gsh[4][2][B];
  __shared__ float hloc[2][B];
  const int tid = threadIdx.x, bk = blockIdx.x;
  const int b = tid & 31, r8 = tid >> 5;
  const int gate = r8 & 3, jj = r8 >> 2;
  const int row = gate * H + bk * 2 + jj;
  const float* wrow = Whh + (size_t)row * H;
  const int bx = b & 7;
  float creg = 0.f;
  for (int t = 0; t < S; ++t){
    if (t > 0 && tid < 64) pollN<4>(htags, tid, (unsigned)t);
    __syncthreads();
    stage_h(h_pp + (size_t)((t + 1) & 1) * BH, hsh, tid);
    __syncthreads();
    float acc = gemv_row(wrow, hsh + b * H, bx);
    float ev = E[((size_t)t * G4 + row) * B + b];
    gsh[gate][jj][b] = acc + ev;
    __syncthreads();
    if (tid < 64){
      int b2 = tid & 31, j2 = tid >> 5;
      float gi = gsh[0][j2][b2], gf = gsh[1][j2][b2];
      float gg = gsh[2][j2][b2], go = gsh[3][j2][b2];
      creg = sigm(gf) * creg + sigm(gi) * tanh_(gg);
      hloc[j2][b2] = sigm(go) * tanh_(creg);
    }
    __syncthreads();
    if (tid < 32){
      float h0 = hloc[0][tid], h1 = hloc[1][tid];
      cstore2(h_pp + (size_t)(t & 1) * BH + (size_t)tid * H + bk * 2, h0, h1);
      *(float2*)(enc_out + ((size_t)tid * S + t) * H + bk * 2) = make_float2(h0, h1);
    }
    __syncthreads();   // drain publishes (vmcnt) before tag
    if (tid == 0) cstoreu(htags + (size_t)bk * 32, (unsigned)(t + 1));
  }
  if (tid < 64){
    int b2 = tid & 31, j2 = tid >> 5;
    c_buf[(size_t)b2 * H + bk * 2 + j2] = creg;
  }
}

// -------- persistent decoder: grid=256, tag dataflow, 3 roles --------
// A (all): 8 gate rows (16KB L1). B (bk<128): 4 W2 rows (8KB L1) -> dp.
// C (128<=bk<160): attention for batch bk-128. Safety: htag(t+1) from block j
// implies j finished A(t) AND B(t-1)/C(t-1) (program order) -> ping-pong
// buffers are safe; top-tag carries its own epoch in bits 8+.
__global__ __launch_bounds__(256) void decoder_kernel(
    const float* __restrict__ Whh,    // dec_Whh [2048][512]
    const float* __restrict__ D,      // [b][t][c]
    const float* __restrict__ dbias,  // [2048]
    const float* __restrict__ W2,     // [512][512]
    const float* __restrict__ Pt,     // [b][h][s]
    const float* __restrict__ vvec,   // [512]
    const float* __restrict__ c_buf,  // [b][h]
    float* __restrict__ h_pp,         // [2][B][H]; h_pp[1] = enc final h
    float* __restrict__ dp,           // [2][B][H]
    unsigned* __restrict__ htags,     // [256] lines
    unsigned* __restrict__ btags,     // [128] lines
    unsigned* __restrict__ tops,      // [32] lines, (epoch<<8)|idx
    float* __restrict__ out)          // [b][t][s]
{
  __shared__ float hsh[BH];
  __shared__ float gsh[4][2][B];
  __shared__ float hloc[2][B];
  __shared__ int   topsh[B];
  __shared__ float dpsh[H];
  __shared__ float vsh[H];
  __shared__ float scsh[2][S];
  __shared__ float wm[2]; __shared__ int wi[2]; __shared__ float wsum[2];
  const int tid = threadIdx.x, bk = blockIdx.x;
  const int b = tid & 31, r8 = tid >> 5;
  const int gate = r8 & 3, jj = r8 >> 2;
  const int row = gate * H + bk * 2 + jj;
  const float* wrow = Whh + (size_t)row * H;
  const int bx = b & 7;
  const int cb = bk - 128;   // C-role batch when 0 <= cb < 32
  float creg = 0.f;
  if (tid < 64) creg = c_buf[(size_t)(tid & 31) * H + bk * 2 + (tid >> 5)];
  if (cb >= 0 && cb < 32){ vsh[tid] = vvec[tid]; vsh[tid + 256] = vvec[tid + 256]; }
  for (int t = 0; t < S; ++t){
    // (a) h(t-1) ready
    if (t > 0 && tid < 64) pollN<4>(htags, tid, (unsigned)t);
    __syncthreads();
    // (b) stage h(t-1)
    stage_h(h_pp + (size_t)((t + 1) & 1) * BH, hsh, tid);
    __syncthreads();
    // (c) gates GEMV
    float acc = gemv_row(wrow, hsh + b * H, bx);
    // (d) top(t-1) poll (hidden behind gemv)
    if (t > 0 && tid < 32){
      unsigned vt;
      do { vt = cloadu(tops + (size_t)tid * 32); } while ((vt >> 8) != (unsigned)t);
      topsh[tid] = (int)(vt & 255u);
    }
    __syncthreads();
    // (e) x-term + pointwise + publish h
    float ev = (t == 0) ? dbias[row]
                        : D[((size_t)b * S + topsh[b]) * G4 + row];
    gsh[gate][jj][b] = acc + ev;
    __syncthreads();
    if (tid < 64){
      int b2 = tid & 31, j2 = tid >> 5;
      float gi = gsh[0][j2][b2], gf = gsh[1][j2][b2];
      float gg = gsh[2][j2][b2], go = gsh[3][j2][b2];
      creg = sigm(gf) * creg + sigm(gi) * tanh_(gg);
      hloc[j2][b2] = sigm(go) * tanh_(creg);
    }
    __syncthreads();
    if (tid < 32)
      cstore2(h_pp + (size_t)(t & 1) * BH + (size_t)tid * H + bk * 2,
              hloc[0][tid], hloc[1][tid]);
    __syncthreads();   // drain before tag
    if (tid == 0) cstoreu(htags + (size_t)bk * 32, (unsigned)(t + 1));
    // (f) B-role: 4 final dp columns
    if (bk < 128){
      if (tid < 64) pollN<4>(htags, tid, (unsigned)(t + 1));
      __syncthreads();
      stage_h(h_pp + (size_t)(t & 1) * BH, hsh, tid);
      __syncthreads();
      if (tid < 128){
        int b2 = tid & 31, nq = tid >> 5;
        int n = bk * 4 + nq;
        float a = gemv_row(W2 + (size_t)n * H, hsh + b2 * H, b2 & 7);
        cstore(dp + (size_t)(t & 1) * BH + (size_t)b2 * H + n, a);
      }
      __syncthreads();   // drain before tag
      if (tid == 0) cstoreu(btags + (size_t)bk * 32, (unsigned)(t + 1));
    }
    // (g) C-role: attention + argmax + log-softmax for batch cb
    if (cb >= 0 && cb < 32){
      if (tid < 64) pollN<2>(btags, tid, (unsigned)(t + 1));
      __syncthreads();
      { float2 d2 = cload2(dp + (size_t)(t & 1) * BH + (size_t)cb * H + tid * 2);
        dpsh[tid * 2] = d2.x; dpsh[tid * 2 + 1] = d2.y; }
      __syncthreads();
      int s = tid & 127, half = tid >> 7;
      const float* Pp = Pt + ((size_t)cb * H + half * 256) * S + s;
      const float* dq = dpsh + half * 256;
      const float* vq = vsh + half * 256;
      float cs = 0.f;
      #pragma unroll 4
      for (int hh = 0; hh < 256; ++hh){
        float x = Pp[(size_t)hh * S] + dq[hh];
        cs = fmaf(vq[hh], tanh_(x), cs);
      }
      scsh[half][s] = cs;
      __syncthreads();
      float sc = 0.f;
      if (tid < 128){
        sc = scsh[0][tid] + scsh[1][tid];
        float mv = sc; int mi = tid;
        #pragma unroll
        for (int off = 32; off > 0; off >>= 1){
          float ov = __shfl_xor(mv, off, 64);
          int   oi = __shfl_xor(mi, off, 64);
          if (ov > mv || (ov == mv && oi < mi)){ mv = ov; mi = oi; }
        }
        if ((tid & 63) == 0){ wm[tid >> 6] = mv; wi[tid >> 6] = mi; }
      }
      __syncthreads();
      float m; int am;
      { float m0 = wm[0], m1 = wm[1];
        if (m1 > m0 || (m1 == m0 && wi[1] < wi[0])){ m = m1; am = wi[1]; }
        else { m = m0; am = wi[0]; } }
      if (tid < 128){
        float se = __expf(sc - m);
        float ss = se;
        #pragma unroll
        for (int off = 32; off > 0; off >>= 1) ss += __shfl_xor(ss, off, 64);
        if ((tid & 63) == 0) wsum[tid >> 6] = ss;
      }
      __syncthreads();
      float lse = __logf(wsum[0] + wsum[1]);
      if (tid < 128) out[((size_t)cb * S + t) * S + tid] = sc - m - lse;
      if (tid == 0)
        cstoreu(tops + (size_t)cb * 32, ((unsigned)(t + 1) << 8) | (unsigned)am);
    }
  }
}

extern "C" void kernel_launch(void* const* d_in, const int* in_sizes, int n_in,
                              void* d_out, int out_size, void* d_ws, size_t ws_size,
                              hipStream_t stream) {
  const float* inputs  = (const float*)d_in[0];
  const float* Wp      = (const float*)d_in[1];
  const float* bp      = (const float*)d_in[2];
  const float* eWih    = (const float*)d_in[3];
  const float* eWhh    = (const float*)d_in[4];
  const float* ebih    = (const float*)d_in[5];
  const float* ebhh    = (const float*)d_in[6];
  const float* dWih    = (const float*)d_in[7];
  const float* dWhh    = (const float*)d_in[8];
  const float* dbih    = (const float*)d_in[9];
  const float* dbhh    = (const float*)d_in[10];
  const float* W1      = (const float*)d_in[11];
  const float* W2      = (const float*)d_in[12];
  const float* v       = (const float*)d_in[13];
  float* out = (float*)d_out;

  float* ws = (float*)d_ws;
  float* E       = ws + OFF_E;    // reused as D after encoder
  float* enc_out = ws + OFF_EO;
  float* Pt      = ws + OFF_PT;
  float* h_pp    = ws + OFF_H;
  float* c_buf   = ws + OFF_CB;
  float* dp      = ws + OFF_DP;
  float* M1      = ws + OFF_M1;
  float* bias_e  = ws + OFF_BE;
  float* dbias   = ws + OFF_DB;
  unsigned* enc_htags = (unsigned*)(ws + OFF_END);
  unsigned* dec_htags = enc_htags + 256 * 32;
  unsigned* btags     = dec_htags + 256 * 32;
  unsigned* tops      = btags + 128 * 32;

  // deterministic per launch: zero h ping-pong + all tag lines
  hipMemsetAsync(h_pp, 0, 2 * (size_t)BH * sizeof(float), stream);
  hipMemsetAsync(enc_htags, 0, CTRL_U32 * sizeof(unsigned), stream);

  prep_misc<<<G4 / 256, 256, 0, stream>>>(eWih, Wp, bp, ebih, ebhh, dbih, dbhh,
                                          M1, bias_e, dbias);
  efill<<<(int)(SZ_E / 256), 256, 0, stream>>>(inputs, M1, bias_e, E);

  encoder_kernel<<<256, 256, 0, stream>>>(eWhh, E, h_pp, c_buf, enc_out, enc_htags);

  // D = enc_out @ dWih^T + dbias (into E's buffer; encoder is done with E)
  float* D = E;
  { dim3 grid(G4 / 64, (B * S) / 64);
    gemm_nt<0><<<grid, 256, 0, stream>>>(enc_out, dWih, dbias, D, B * S, G4, H); }
  { dim3 grid(H / 64, (B * S) / 64);
    gemm_nt<1><<<grid, 256, 0, stream>>>(enc_out, W1, nullptr, Pt, B * S, H, H); }

  decoder_kernel<<<256, 256, 0, stream>>>(dWhh, D, dbias, W2, Pt, v, c_buf,
                                          h_pp, dp, dec_htags, btags, tops, out);
  (void)in_sizes; (void)n_in; (void)out_size; (void)ws_size;
}